// Round 10
// baseline (429.734 us; speedup 1.0000x reference)
//
#include <hip/hip_runtime.h>
#include <math.h>

#define NN 50000
#define NE 800000
#define SB2 2048  // score blocks
#define LB 1024   // loss blocks
#define CAP 64    // bucket capacity per node

using bf16x8 = __attribute__((ext_vector_type(8))) short;
using f32x4  = __attribute__((ext_vector_type(4))) float;
using f32x2  = __attribute__((ext_vector_type(2))) float;
using i32x8  = __attribute__((ext_vector_type(8))) int;

__device__ __forceinline__ float b2f(short s) {
    union { unsigned u; float f; } v;
    v.u = ((unsigned)(unsigned short)s) << 16;
    return v.f;
}
__device__ __forceinline__ unsigned short f2b(float f) {
    union { float f; unsigned u; } v;
    v.f = f;
    unsigned r = v.u + 0x7fffu + ((v.u >> 16) & 1u);
    return (unsigned short)(r >> 16);
}
__device__ __forceinline__ unsigned char f2e4m3(float f) {
    return (unsigned char)(__builtin_amdgcn_cvt_pk_fp8_f32(f, f, 0, false) & 0xff);
}
__device__ __forceinline__ void acc8(float* acc, uint2 u) {
    f32x2 p0 = __builtin_amdgcn_cvt_pk_f32_fp8(u.x, false);
    f32x2 p1 = __builtin_amdgcn_cvt_pk_f32_fp8(u.x, true);
    f32x2 p2 = __builtin_amdgcn_cvt_pk_f32_fp8(u.y, false);
    f32x2 p3 = __builtin_amdgcn_cvt_pk_f32_fp8(u.y, true);
    acc[0] += p0.x; acc[1] += p0.y;
    acc[2] += p1.x; acc[3] += p1.y;
    acc[4] += p2.x; acc[5] += p2.y;
    acc[6] += p3.x; acc[7] += p3.y;
}

// ------- fused: degs (src) + bucket fill keyed by dst (u16 src entries) ------
__global__ void k_build(const int* __restrict__ ei, int* __restrict__ degs,
                        int* __restrict__ cnt, unsigned short* __restrict__ bkt16) {
    int e = blockIdx.x * 256 + threadIdx.x;
    if (e < NE) {
        int s = ei[e], d = ei[NE + e];
        atomicAdd(&degs[s], 1);
        int slot = atomicAdd(&cnt[d], 1);
        if (slot < CAP) bkt16[(d << 6) + slot] = (unsigned short)s;
    }
}

// ------- fused prep: conv_x (xcat + dis-scaled xf8), dis, weight frags ------
__global__ __launch_bounds__(256) void k_prep(const float* __restrict__ x,
                                              unsigned short* __restrict__ xcat,
                                              unsigned char* __restrict__ xf8,
                                              const int* __restrict__ degs,
                                              float* __restrict__ dis,
                                              const float* __restrict__ W1_0,
                                              const float* __restrict__ W1_1,
                                              const float* __restrict__ W2_0,
                                              const float* __restrict__ W2_1,
                                              const float* __restrict__ L1,
                                              const float* __restrict__ L2,
                                              unsigned short* __restrict__ Wt1f,
                                              unsigned short* __restrict__ Wt2f,
                                              unsigned short* __restrict__ Wtlf) {
    int b = blockIdx.x;
    if (b < 12500) {  // conv_x
        int t = b * 256 + threadIdx.x;
        int n = t >> 6, k = t & 63;
        float v = (k < 58) ? x[(size_t)n * 58 + k] : 0.0f;
        xcat[(size_t)n * 128 + k] = f2b(v);
        int dg = degs[n];
        float dv = dg > 0 ? 1.0f / sqrtf((float)dg) : 0.0f;
        xf8[(size_t)n * 64 + k] = f2e4m3(dv * v);
        return;
    }
    if (b < 12696) {  // dis
        int i = (b - 12500) * 256 + threadIdx.x;
        if (i < NN) {
            int dg = degs[i];
            dis[i] = dg > 0 ? 1.0f / sqrtf((float)dg) : 0.0f;
        }
        return;
    }
    int t = (b - 12696) * 256 + threadIdx.x;
    if (t < 40960) {  // Wt1f: 20 nt x 4 frags x 512
        int f = t >> 9, lane = (t >> 3) & 63, j = t & 7;
        int nt = f >> 2, s = f & 3;
        int ml = lane & 15, quad = lane >> 4;
        int k = s * 32 + quad * 8 + j;
        int col = nt * 16 + ml;
        float v = 0.0f;
        if (col < 300) {
            if (k < 58) v = W1_0[k * 300 + col];
            else if (k >= 64 && k < 122) v = W1_1[(k - 64) * 300 + col];
        }
        Wt1f[t] = f2b(v);
    } else if (t < 107520) {  // Wt2f: 13 nt x 10 frags x 512
        int u = t - 40960;
        int f = u >> 9, lane = (u >> 3) & 63, j = u & 7;
        int nt = f / 10, s = f - nt * 10;
        int ml = lane & 15, quad = lane >> 4;
        int k = s * 32 + quad * 8 + j;
        int col = nt * 16 + ml;
        float v = 0.0f;
        if (k < 300) {
            if (col < 100) v = W2_0[k * 100 + col];
            else if (col >= 104 && col < 204) v = W2_1[k * 100 + (col - 104)];
        }
        Wt2f[u] = f2b(v);
    } else if (t < 120832) {  // Wtlf: 13 nt x 2 frags x 512
        int u = t - 107520;
        int f = u >> 9, lane = (u >> 3) & 63, j = u & 7;
        int nt = f >> 1, s = f & 1;
        int ml = lane & 15, quad = lane >> 4;
        int k = s * 32 + quad * 8 + j;
        int col = nt * 16 + ml;
        float v = 0.0f;
        if (k < 58) {
            if (col < 100) v = L1[col * 58 + k];
            else if (col >= 104 && col < 204) v = L2[(col - 104) * 58 + k];
        }
        Wtlf[u] = f2b(v);
    }
}

// ------- gather58: tx1[n] = -dis[n] * sum xf8'(src), xcat cols 64..127 -------
__global__ __launch_bounds__(256) void k_gather58(const int* __restrict__ cnt,
                                                  const unsigned short* __restrict__ bkt16,
                                                  const float* __restrict__ dis,
                                                  const unsigned char* __restrict__ xf8,
                                                  unsigned short* __restrict__ xcat) {
    int t = blockIdx.x * 256 + threadIdx.x;
    int n = t >> 3, l = t & 7;
    if (n >= NN) return;
    int c = cnt[n]; if (c > CAP) c = CAP;
    float dn = dis[n];
    const unsigned short* bp = bkt16 + (n << 6);
    float acc[8] = {0, 0, 0, 0, 0, 0, 0, 0};
    for (int i = 0; i < c; i++) {
        unsigned src = bp[i];
        uint2 u = *(const uint2*)(xf8 + (size_t)src * 64 + l * 8);
        acc8(acc, u);
    }
    bf16x8 o;
#pragma unroll
    for (int j = 0; j < 8; j++) o[j] = (short)f2b(-dn * acc[j]);
    *(bf16x8*)(xcat + (size_t)n * 128 + 64 + l * 8) = o;
}

// ------- fused MFMA GEMM: h in LDS; hp = h@W2_0 (fp32), hwf8' = dis*h@W2_1 ---
__global__ __launch_bounds__(256) void k_mm12(const unsigned short* __restrict__ xcat,
                                              const unsigned short* __restrict__ Wt1f,
                                              const float* __restrict__ b1,
                                              const unsigned short* __restrict__ Wt2f,
                                              const float* __restrict__ dis,
                                              float* __restrict__ hp,
                                              unsigned char* __restrict__ hwf8) {
    __shared__ __attribute__((aligned(16))) unsigned short hs[64 * 328];
    __shared__ __attribute__((aligned(16))) unsigned short bst[2][5120];
    int tid = threadIdx.x;
    int wave = tid >> 6, lane = tid & 63, ml = lane & 15, quad = lane >> 4;
    int row0 = blockIdx.x * 64;
    int rw = row0 + wave * 16;

    int ar = rw + ml; if (ar >= NN) ar = NN - 1;
    const bf16x8* Ap = (const bf16x8*)(xcat + (size_t)ar * 128 + quad * 8);
    bf16x8 a0 = Ap[0], a1 = Ap[4], a2 = Ap[8], a3 = Ap[12];
    float dv[4];
#pragma unroll
    for (int r = 0; r < 4; r++) {
        int row = rw + quad * 4 + r;
        dv[r] = dis[row < NN ? row : NN - 1];
    }

    ((bf16x8*)bst[0])[tid] = ((const bf16x8*)Wt1f)[tid];
    __syncthreads();

    for (int nt = 0; nt < 20; nt++) {
        if (nt + 1 < 20)
            ((bf16x8*)bst[(nt + 1) & 1])[tid] =
                ((const bf16x8*)(Wt1f + (size_t)(nt + 1) * 2048))[tid];
        const bf16x8* Bp = (const bf16x8*)bst[nt & 1];
        f32x4 acc = {0.f, 0.f, 0.f, 0.f};
        acc = __builtin_amdgcn_mfma_f32_16x16x32_bf16(a0, Bp[0 * 64 + lane], acc, 0, 0, 0);
        acc = __builtin_amdgcn_mfma_f32_16x16x32_bf16(a1, Bp[1 * 64 + lane], acc, 0, 0, 0);
        acc = __builtin_amdgcn_mfma_f32_16x16x32_bf16(a2, Bp[2 * 64 + lane], acc, 0, 0, 0);
        acc = __builtin_amdgcn_mfma_f32_16x16x32_bf16(a3, Bp[3 * 64 + lane], acc, 0, 0, 0);
        int col = nt * 16 + ml;
        float bias = (col < 300) ? b1[col] : 0.0f;
#pragma unroll
        for (int r = 0; r < 4; r++) {
            float v = acc[r] + bias;
            v = v > 0.0f ? v : 0.0f;
            if (col >= 300) v = 0.0f;
            hs[(wave * 16 + quad * 4 + r) * 328 + col] = f2b(v);
        }
        __syncthreads();
    }

    for (int i = tid; i < 640; i += 256)
        ((bf16x8*)bst[0])[i] = ((const bf16x8*)Wt2f)[i];
    bf16x8 A2[10];
#pragma unroll
    for (int s = 0; s < 10; s++)
        A2[s] = *(const bf16x8*)(hs + (wave * 16 + ml) * 328 + s * 32 + quad * 8);
    __syncthreads();

    for (int nt = 0; nt < 13; nt++) {
        if (nt + 1 < 13)
            for (int i = tid; i < 640; i += 256)
                ((bf16x8*)bst[(nt + 1) & 1])[i] =
                    ((const bf16x8*)(Wt2f + (size_t)(nt + 1) * 5120))[i];
        const bf16x8* Bp = (const bf16x8*)bst[nt & 1];
        f32x4 acc = {0.f, 0.f, 0.f, 0.f};
#pragma unroll
        for (int s = 0; s < 10; s++)
            acc = __builtin_amdgcn_mfma_f32_16x16x32_bf16(A2[s], Bp[s * 64 + lane], acc, 0, 0, 0);
        int j = nt * 16 + ml;
#pragma unroll
        for (int r = 0; r < 4; r++) {
            int row = rw + quad * 4 + r;
            if (row < NN) {
                if (j < 104) hp[(size_t)row * 104 + j] = acc[r];
                else hwf8[(size_t)row * 128 + (j - 104)] = f2e4m3(dv[r] * acc[r]);
            }
        }
        __syncthreads();
    }
}

// ------- fused: tx2 gather (LDS) + lin MFMA + x1 epilogue + layer3 dots ------
__global__ __launch_bounds__(256) void k_mmlin2(const unsigned short* __restrict__ xcat,
                                                const unsigned short* __restrict__ Wtlf,
                                                const float* __restrict__ hp,
                                                const unsigned char* __restrict__ hwf8,
                                                const int* __restrict__ cnt,
                                                const unsigned short* __restrict__ bkt16,
                                                const float* __restrict__ dis,
                                                const float* __restrict__ b2,
                                                const float* __restrict__ l1b,
                                                const float* __restrict__ l2b,
                                                const float* __restrict__ W30,
                                                const float* __restrict__ W31,
                                                const float* __restrict__ b3,
                                                float* __restrict__ out,
                                                float* __restrict__ qbuf,
                                                unsigned char* __restrict__ zf8) {
    __shared__ float tx2s[64 * 104];  // 26.6 KB
    int tid = threadIdx.x;
    int wave = tid >> 6, lane = tid & 63, ml = lane & 15, quad = lane >> 4;
    int row0 = blockIdx.x * 64;
    int rw = row0 + wave * 16;

    // phase A: gather tx2 for the block's 64 rows into LDS
    {
        int l = tid & 15, nd0 = tid >> 4;
        for (int sub = 0; sub < 4; sub++) {
            int nd = sub * 16 + nd0;
            int node = row0 + nd;
            if (node < NN && l < 13) {
                int c = cnt[node]; if (c > CAP) c = CAP;
                float dn = dis[node];
                const unsigned short* bp = bkt16 + (node << 6);
                float acc[8] = {0, 0, 0, 0, 0, 0, 0, 0};
                for (int i = 0; i < c; i++) {
                    unsigned src = bp[i];
                    uint2 u = *(const uint2*)(hwf8 + (size_t)src * 128 + l * 8);
                    acc8(acc, u);
                }
#pragma unroll
                for (int j = 0; j < 8; j++) tx2s[nd * 104 + l * 8 + j] = -dn * acc[j];
            }
        }
    }
    __syncthreads();

    int ar = rw + ml; if (ar >= NN) ar = NN - 1;
    const bf16x8* Ap = (const bf16x8*)(xcat + (size_t)ar * 128 + quad * 8);
    bf16x8 a0 = Ap[0], a1 = Ap[4];
    float p0[4] = {0, 0, 0, 0}, p1[4] = {0, 0, 0, 0};
    float b3v = b3[0];

    for (int nt = 0; nt < 13; nt++) {
        bf16x8 bw0 = *(const bf16x8*)(Wtlf + (size_t)((nt * 2 + 0) * 64 + lane) * 8);
        bf16x8 bw1 = *(const bf16x8*)(Wtlf + (size_t)((nt * 2 + 1) * 64 + lane) * 8);
        f32x4 acc = {0.f, 0.f, 0.f, 0.f};
        acc = __builtin_amdgcn_mfma_f32_16x16x32_bf16(a0, bw0, acc, 0, 0, 0);
        acc = __builtin_amdgcn_mfma_f32_16x16x32_bf16(a1, bw1, acc, 0, 0, 0);
        int j = nt * 16 + ml;
        int jj = (j < 104) ? j : j - 104;
        float bb = 0.0f, lb = 0.0f;
        if (jj < 100) {
            bb = b2[jj];
            lb = (j < 104) ? l1b[jj] : l2b[jj];
        }
        float w0 = (j < 100) ? W30[j] : 0.0f;
        float w1 = (j < 100) ? W31[j] : 0.0f;
#pragma unroll
        for (int r = 0; r < 4; r++) {
            int row = rw + quad * 4 + r;
            int rcl = row < NN ? row : NN - 1;
            float x1v = hp[(size_t)rcl * 104 + jj] + tx2s[(wave * 16 + quad * 4 + r) * 104 + jj] + bb;
            x1v = x1v > 0.0f ? x1v : 0.0f;
            float lv = acc[r] + lb;
            lv = lv > 0.0f ? lv : 0.0f;
            float o = x1v + lv;
            if (j < 104) {
                p0[r] += o * w0;
                p1[r] += o * w1;
            } else if (row < NN) {
                zf8[(size_t)row * 128 + (j - 104)] = f2e4m3(o);
            }
        }
    }
#pragma unroll
    for (int m = 1; m < 16; m <<= 1) {
#pragma unroll
        for (int r = 0; r < 4; r++) {
            p0[r] += __shfl_xor(p0[r], m, 64);
            p1[r] += __shfl_xor(p1[r], m, 64);
        }
    }
    if (ml == 0) {
#pragma unroll
        for (int r = 0; r < 4; r++) {
            int row = rw + quad * 4 + r;
            if (row < NN) {
                out[row] = p0[r] + b3v;
                qbuf[row] = dis[row] * p1[r];
            }
        }
    }
    for (int idx = tid; idx < 64 * 6; idx += 256) {
        int rr = row0 + idx / 6;
        if (rr < NN) *(unsigned*)(zf8 + (size_t)rr * 128 + 104 + (idx % 6) * 4) = 0u;
    }
}

// ------- pure edge scores via fp8 MFMA -> pbuf ----------
__global__ __launch_bounds__(256) void k_score(const unsigned char* __restrict__ zf8,
                                               const int* __restrict__ ei,
                                               const int* __restrict__ nei,
                                               float* __restrict__ pbuf) {
    int lane = threadIdx.x & 63;
    int wid = (blockIdx.x * 256 + threadIdx.x) >> 6;
    int nw = SB2 * 4;
    int ml = lane & 15, quad = lane >> 4;
    int dr = ml - quad * 4;
    bool diag = (dr >= 0 && dr < 4);
    const int G = (2 * NE) / 16;
    for (int g = wid; g < G; g += nw) {
        int base = g * 16;
        int a, b;
        if (base < NE) {
            a = ei[base + ml];
            b = ei[NE + base + ml];
        } else {
            a = nei[base - NE + ml];
            b = nei[base + ml];
        }
        i32x8 av = *(const i32x8*)(zf8 + (size_t)a * 128 + quad * 32);
        i32x8 bv = *(const i32x8*)(zf8 + (size_t)b * 128 + quad * 32);
        f32x4 d = {0.f, 0.f, 0.f, 0.f};
        d = __builtin_amdgcn_mfma_scale_f32_16x16x128_f8f6f4(
                av, bv, d, 0, 0, 0, 0x7f7f7f7f, 0, 0x7f7f7f7f);
        if (diag) pbuf[base + ml] = d[dr];
    }
}

// ------- dense transcendentals + block partial sums ----------
__global__ __launch_bounds__(256) void k_loss(const float* __restrict__ pbuf,
                                              double* __restrict__ red) {
    double acc = 0.0;
    for (int i = blockIdx.x * 256 + threadIdx.x; i < 2 * NE; i += LB * 256) {
        float p = pbuf[i];
        float sg = 1.0f / (1.0f + expf(-p));
        float term = (i < NE) ? logf(sg + 1e-15f) : logf(1.0f - sg + 1e-15f);
        acc += (double)term;
    }
    __shared__ double sred[256];
    sred[threadIdx.x] = acc;
    __syncthreads();
    for (int s = 128; s; s >>= 1) {
        if (threadIdx.x < s) sred[threadIdx.x] += sred[threadIdx.x + s];
        __syncthreads();
    }
    if (threadIdx.x == 0) red[blockIdx.x] = sred[0];
}

// ------- fused: final loss reduction (block 0) + layer3 gather (rest) --------
__global__ __launch_bounds__(256) void k_final_g1(const double* __restrict__ red,
                                                  const float* __restrict__ c1,
                                                  const float* __restrict__ c2,
                                                  const int* __restrict__ cnt,
                                                  const unsigned short* __restrict__ bkt16,
                                                  const float* __restrict__ dis,
                                                  const float* __restrict__ qbuf,
                                                  float* __restrict__ out) {
    if (blockIdx.x == 0) {
        double a = 0.0;
        for (int i = threadIdx.x; i < LB; i += 256) a += red[i];
        __shared__ double sred[256];
        sred[threadIdx.x] = a;
        __syncthreads();
        for (int st = 128; st; st >>= 1) {
            if (threadIdx.x < st) sred[threadIdx.x] += sred[threadIdx.x + st];
            __syncthreads();
        }
        if (threadIdx.x == 0) {
            out[NN] = (float)(-sred[0] / (double)NE);
            out[NN + 1] = c1[0];
            out[NN + 2] = c2[0];
        }
        return;
    }
    int n = (blockIdx.x - 1) * 256 + threadIdx.x;
    if (n >= NN) return;
    int c = cnt[n]; if (c > CAP) c = CAP;
    const unsigned short* bp = bkt16 + (n << 6);
    float acc = 0.0f;
    for (int i = 0; i < c; i++) acc += qbuf[bp[i]];
    out[n] += -dis[n] * acc;
}

extern "C" void kernel_launch(void* const* d_in, const int* in_sizes, int n_in,
                              void* d_out, int out_size, void* d_ws, size_t ws_size,
                              hipStream_t stream) {
    const float* x    = (const float*)d_in[0];
    const int*   ei   = (const int*)d_in[1];
    const int*   nei  = (const int*)d_in[2];
    const float* W1_0 = (const float*)d_in[3];
    const float* W1_1 = (const float*)d_in[4];
    const float* b1   = (const float*)d_in[5];
    const float* W2_0 = (const float*)d_in[6];
    const float* W2_1 = (const float*)d_in[7];
    const float* b2   = (const float*)d_in[8];
    const float* W3_0 = (const float*)d_in[9];
    const float* W3_1 = (const float*)d_in[10];
    const float* b3   = (const float*)d_in[11];
    const float* l1W  = (const float*)d_in[12];
    const float* l1b  = (const float*)d_in[13];
    const float* l2W  = (const float*)d_in[14];
    const float* l2b  = (const float*)d_in[15];
    const float* c1   = (const float*)d_in[16];
    const float* c2   = (const float*)d_in[17];
    float* out = (float*)d_out;
    float* w = (float*)d_ws;

    // workspace (float offsets)
    unsigned short* bkt16  = (unsigned short*)w;                  // NN*64 u16
    int*            degs   = (int*)(w + 1600000);                 // 50000 [zeroed]
    int*            cnt    = (int*)(w + 1650000);                 // 50000 [zeroed]
    float*          dis    = w + 1700000;                         // 50000
    float*          qbuf   = w + 1750000;                         // 50000
    double*         red    = (double*)(w + 1800000);              // 1024 doubles
    float*          pbuf   = w + 1802048;                         // 1.6M floats
    unsigned short* xcat   = (unsigned short*)(w + 3402048);      // N*128 bf16
    unsigned short* Wt1f   = (unsigned short*)(w + 6602048);      // 40960 bf16
    unsigned short* Wt2f   = (unsigned short*)(w + 6622528);      // 66560 bf16
    unsigned short* Wtlf   = (unsigned short*)(w + 6655808);      // 13312 bf16
    float*          hp     = w + 6662464;                         // N*104 f
    unsigned char*  hwf8   = (unsigned char*)(w + 11862464);      // N*128 bytes
    unsigned char*  zf8    = (unsigned char*)(w + 13462464);      // N*128 bytes
    unsigned char*  xf8    = (unsigned char*)(w + 15062464);      // N*64 bytes

    hipMemsetAsync(degs, 0, 100000 * sizeof(int), stream);  // degs + cnt contiguous

    k_build<<<(NE + 255) / 256, 256, 0, stream>>>(ei, degs, cnt, bkt16);
    k_prep<<<13168, 256, 0, stream>>>(x, xcat, xf8, degs, dis,
                                      W1_0, W1_1, W2_0, W2_1, l1W, l2W,
                                      Wt1f, Wt2f, Wtlf);

    k_gather58<<<(NN * 8 + 255) / 256, 256, 0, stream>>>(cnt, bkt16, dis, xf8, xcat);
    k_mm12<<<(NN + 63) / 64, 256, 0, stream>>>(xcat, Wt1f, b1, Wt2f, dis, hp, hwf8);

    k_mmlin2<<<(NN + 63) / 64, 256, 0, stream>>>(xcat, Wtlf, hp, hwf8, cnt, bkt16, dis,
                                                 b2, l1b, l2b, W3_0, W3_1, b3,
                                                 out, qbuf, zf8);

    k_score<<<SB2, 256, 0, stream>>>(zf8, ei, nei, pbuf);
    k_loss<<<LB, 256, 0, stream>>>(pbuf, red);
    k_final_g1<<<1 + (NN + 255) / 256, 256, 0, stream>>>(red, c1, c2, cnt, bkt16, dis, qbuf, out);
}

// Round 11
// 369.527 us; speedup vs baseline: 1.1629x; 1.1629x over previous
//
#include <hip/hip_runtime.h>
#include <math.h>

#define NN 50000
#define NE 800000
#define SB2 2048  // score blocks
#define LB 1024   // loss blocks
#define CAP 64    // bucket capacity per node

using bf16x8 = __attribute__((ext_vector_type(8))) short;
using f32x4  = __attribute__((ext_vector_type(4))) float;
using f32x2  = __attribute__((ext_vector_type(2))) float;
using i32x8  = __attribute__((ext_vector_type(8))) int;

__device__ __forceinline__ float b2f(short s) {
    union { unsigned u; float f; } v;
    v.u = ((unsigned)(unsigned short)s) << 16;
    return v.f;
}
__device__ __forceinline__ unsigned short f2b(float f) {
    union { float f; unsigned u; } v;
    v.f = f;
    unsigned r = v.u + 0x7fffu + ((v.u >> 16) & 1u);
    return (unsigned short)(r >> 16);
}
__device__ __forceinline__ unsigned char f2e4m3(float f) {
    return (unsigned char)(__builtin_amdgcn_cvt_pk_fp8_f32(f, f, 0, false) & 0xff);
}
__device__ __forceinline__ void acc8(float* acc, uint2 u) {
    f32x2 p0 = __builtin_amdgcn_cvt_pk_f32_fp8(u.x, false);
    f32x2 p1 = __builtin_amdgcn_cvt_pk_f32_fp8(u.x, true);
    f32x2 p2 = __builtin_amdgcn_cvt_pk_f32_fp8(u.y, false);
    f32x2 p3 = __builtin_amdgcn_cvt_pk_f32_fp8(u.y, true);
    acc[0] += p0.x; acc[1] += p0.y;
    acc[2] += p1.x; acc[3] += p1.y;
    acc[4] += p2.x; acc[5] += p2.y;
    acc[6] += p3.x; acc[7] += p3.y;
}

// ------- fused: degs (src) + bucket fill keyed by dst (u16 src entries) ------
__global__ void k_build(const int* __restrict__ ei, int* __restrict__ degs,
                        int* __restrict__ cnt, unsigned short* __restrict__ bkt16) {
    int e = blockIdx.x * 256 + threadIdx.x;
    if (e < NE) {
        int s = ei[e], d = ei[NE + e];
        atomicAdd(&degs[s], 1);
        int slot = atomicAdd(&cnt[d], 1);
        if (slot < CAP) bkt16[(d << 6) + slot] = (unsigned short)s;
    }
}

// ------- fused prep: conv_x (xcat + dis-scaled xf8), dis, weight frags ------
__global__ __launch_bounds__(256) void k_prep(const float* __restrict__ x,
                                              unsigned short* __restrict__ xcat,
                                              unsigned char* __restrict__ xf8,
                                              const int* __restrict__ degs,
                                              float* __restrict__ dis,
                                              const float* __restrict__ W1_0,
                                              const float* __restrict__ W1_1,
                                              const float* __restrict__ W2_0,
                                              const float* __restrict__ W2_1,
                                              const float* __restrict__ L1,
                                              const float* __restrict__ L2,
                                              unsigned short* __restrict__ Wt1f,
                                              unsigned short* __restrict__ Wt2f,
                                              unsigned short* __restrict__ Wtlf) {
    int b = blockIdx.x;
    if (b < 12500) {  // conv_x
        int t = b * 256 + threadIdx.x;
        int n = t >> 6, k = t & 63;
        float v = (k < 58) ? x[(size_t)n * 58 + k] : 0.0f;
        xcat[(size_t)n * 128 + k] = f2b(v);
        int dg = degs[n];
        float dv = dg > 0 ? 1.0f / sqrtf((float)dg) : 0.0f;
        xf8[(size_t)n * 64 + k] = f2e4m3(dv * v);
        return;
    }
    if (b < 12696) {  // dis
        int i = (b - 12500) * 256 + threadIdx.x;
        if (i < NN) {
            int dg = degs[i];
            dis[i] = dg > 0 ? 1.0f / sqrtf((float)dg) : 0.0f;
        }
        return;
    }
    int t = (b - 12696) * 256 + threadIdx.x;
    if (t < 40960) {  // Wt1f: 20 nt x 4 frags x 512
        int f = t >> 9, lane = (t >> 3) & 63, j = t & 7;
        int nt = f >> 2, s = f & 3;
        int ml = lane & 15, quad = lane >> 4;
        int k = s * 32 + quad * 8 + j;
        int col = nt * 16 + ml;
        float v = 0.0f;
        if (col < 300) {
            if (k < 58) v = W1_0[k * 300 + col];
            else if (k >= 64 && k < 122) v = W1_1[(k - 64) * 300 + col];
        }
        Wt1f[t] = f2b(v);
    } else if (t < 107520) {  // Wt2f: 13 nt x 10 frags x 512
        int u = t - 40960;
        int f = u >> 9, lane = (u >> 3) & 63, j = u & 7;
        int nt = f / 10, s = f - nt * 10;
        int ml = lane & 15, quad = lane >> 4;
        int k = s * 32 + quad * 8 + j;
        int col = nt * 16 + ml;
        float v = 0.0f;
        if (k < 300) {
            if (col < 100) v = W2_0[k * 100 + col];
            else if (col >= 104 && col < 204) v = W2_1[k * 100 + (col - 104)];
        }
        Wt2f[u] = f2b(v);
    } else if (t < 120832) {  // Wtlf: 13 nt x 2 frags x 512
        int u = t - 107520;
        int f = u >> 9, lane = (u >> 3) & 63, j = u & 7;
        int nt = f >> 1, s = f & 1;
        int ml = lane & 15, quad = lane >> 4;
        int k = s * 32 + quad * 8 + j;
        int col = nt * 16 + ml;
        float v = 0.0f;
        if (k < 58) {
            if (col < 100) v = L1[col * 58 + k];
            else if (col >= 104 && col < 204) v = L2[(col - 104) * 58 + k];
        }
        Wtlf[u] = f2b(v);
    }
}

// ------- gather58: tx1[n] = -dis[n] * sum xf8'(src), xcat cols 64..127 -------
__global__ __launch_bounds__(256) void k_gather58(const int* __restrict__ cnt,
                                                  const unsigned short* __restrict__ bkt16,
                                                  const float* __restrict__ dis,
                                                  const unsigned char* __restrict__ xf8,
                                                  unsigned short* __restrict__ xcat) {
    int t = blockIdx.x * 256 + threadIdx.x;
    int n = t >> 3, l = t & 7;
    if (n >= NN) return;
    int c = cnt[n]; if (c > CAP) c = CAP;
    float dn = dis[n];
    const unsigned short* bp = bkt16 + (n << 6);
    float acc[8] = {0, 0, 0, 0, 0, 0, 0, 0};
    for (int i = 0; i < c; i++) {
        unsigned src = bp[i];
        uint2 u = *(const uint2*)(xf8 + (size_t)src * 64 + l * 8);
        acc8(acc, u);
    }
    bf16x8 o;
#pragma unroll
    for (int j = 0; j < 8; j++) o[j] = (short)f2b(-dn * acc[j]);
    *(bf16x8*)(xcat + (size_t)n * 128 + 64 + l * 8) = o;
}

// ------- fused MFMA GEMM: h in LDS; hp = h@W2_0 (fp32), hwf8' = dis*h@W2_1 ---
__global__ __launch_bounds__(256) void k_mm12(const unsigned short* __restrict__ xcat,
                                              const unsigned short* __restrict__ Wt1f,
                                              const float* __restrict__ b1,
                                              const unsigned short* __restrict__ Wt2f,
                                              const float* __restrict__ dis,
                                              float* __restrict__ hp,
                                              unsigned char* __restrict__ hwf8) {
    __shared__ __attribute__((aligned(16))) unsigned short hs[64 * 328];
    __shared__ __attribute__((aligned(16))) unsigned short bst[2][5120];
    int tid = threadIdx.x;
    int wave = tid >> 6, lane = tid & 63, ml = lane & 15, quad = lane >> 4;
    int row0 = blockIdx.x * 64;
    int rw = row0 + wave * 16;

    int ar = rw + ml; if (ar >= NN) ar = NN - 1;
    const bf16x8* Ap = (const bf16x8*)(xcat + (size_t)ar * 128 + quad * 8);
    bf16x8 a0 = Ap[0], a1 = Ap[4], a2 = Ap[8], a3 = Ap[12];
    float dv[4];
#pragma unroll
    for (int r = 0; r < 4; r++) {
        int row = rw + quad * 4 + r;
        dv[r] = dis[row < NN ? row : NN - 1];
    }

    ((bf16x8*)bst[0])[tid] = ((const bf16x8*)Wt1f)[tid];
    __syncthreads();

    for (int nt = 0; nt < 20; nt++) {
        if (nt + 1 < 20)
            ((bf16x8*)bst[(nt + 1) & 1])[tid] =
                ((const bf16x8*)(Wt1f + (size_t)(nt + 1) * 2048))[tid];
        const bf16x8* Bp = (const bf16x8*)bst[nt & 1];
        f32x4 acc = {0.f, 0.f, 0.f, 0.f};
        acc = __builtin_amdgcn_mfma_f32_16x16x32_bf16(a0, Bp[0 * 64 + lane], acc, 0, 0, 0);
        acc = __builtin_amdgcn_mfma_f32_16x16x32_bf16(a1, Bp[1 * 64 + lane], acc, 0, 0, 0);
        acc = __builtin_amdgcn_mfma_f32_16x16x32_bf16(a2, Bp[2 * 64 + lane], acc, 0, 0, 0);
        acc = __builtin_amdgcn_mfma_f32_16x16x32_bf16(a3, Bp[3 * 64 + lane], acc, 0, 0, 0);
        int col = nt * 16 + ml;
        float bias = (col < 300) ? b1[col] : 0.0f;
#pragma unroll
        for (int r = 0; r < 4; r++) {
            float v = acc[r] + bias;
            v = v > 0.0f ? v : 0.0f;
            if (col >= 300) v = 0.0f;
            hs[(wave * 16 + quad * 4 + r) * 328 + col] = f2b(v);
        }
        __syncthreads();
    }

    for (int i = tid; i < 640; i += 256)
        ((bf16x8*)bst[0])[i] = ((const bf16x8*)Wt2f)[i];
    bf16x8 A2[10];
#pragma unroll
    for (int s = 0; s < 10; s++)
        A2[s] = *(const bf16x8*)(hs + (wave * 16 + ml) * 328 + s * 32 + quad * 8);
    __syncthreads();

    for (int nt = 0; nt < 13; nt++) {
        if (nt + 1 < 13)
            for (int i = tid; i < 640; i += 256)
                ((bf16x8*)bst[(nt + 1) & 1])[i] =
                    ((const bf16x8*)(Wt2f + (size_t)(nt + 1) * 5120))[i];
        const bf16x8* Bp = (const bf16x8*)bst[nt & 1];
        f32x4 acc = {0.f, 0.f, 0.f, 0.f};
#pragma unroll
        for (int s = 0; s < 10; s++)
            acc = __builtin_amdgcn_mfma_f32_16x16x32_bf16(A2[s], Bp[s * 64 + lane], acc, 0, 0, 0);
        int j = nt * 16 + ml;
#pragma unroll
        for (int r = 0; r < 4; r++) {
            int row = rw + quad * 4 + r;
            if (row < NN) {
                if (j < 104) hp[(size_t)row * 104 + j] = acc[r];
                else hwf8[(size_t)row * 128 + (j - 104)] = f2e4m3(dv[r] * acc[r]);
            }
        }
        __syncthreads();
    }
}

// ------- gather100 standalone: tx2[n] = -dis[n]*sum hwf8'(src), fp32 out -----
__global__ __launch_bounds__(256) void k_gather100(const int* __restrict__ cnt,
                                                   const unsigned short* __restrict__ bkt16,
                                                   const float* __restrict__ dis,
                                                   const unsigned char* __restrict__ hwf8,
                                                   float* __restrict__ tx2) {
    int t = blockIdx.x * 256 + threadIdx.x;
    int n = t >> 4, l = t & 15;
    if (n >= NN || l >= 13) return;
    int c = cnt[n]; if (c > CAP) c = CAP;
    float dn = dis[n];
    const unsigned short* bp = bkt16 + (n << 6);
    float acc[8] = {0, 0, 0, 0, 0, 0, 0, 0};
    for (int i = 0; i < c; i++) {
        unsigned src = bp[i];
        uint2 u = *(const uint2*)(hwf8 + (size_t)src * 128 + l * 8);
        acc8(acc, u);
    }
    f32x4 o0 = {-dn * acc[0], -dn * acc[1], -dn * acc[2], -dn * acc[3]};
    f32x4 o1 = {-dn * acc[4], -dn * acc[5], -dn * acc[6], -dn * acc[7]};
    *(f32x4*)(tx2 + (size_t)n * 104 + l * 8) = o0;
    *(f32x4*)(tx2 + (size_t)n * 104 + l * 8 + 4) = o1;
}

// ------- lin MFMA + x1 epilogue + fused layer3 dots (no LDS) -----------------
__global__ __launch_bounds__(256) void k_mmlin3(const unsigned short* __restrict__ xcat,
                                                const unsigned short* __restrict__ Wtlf,
                                                const float* __restrict__ hp,
                                                const float* __restrict__ tx2,
                                                const float* __restrict__ dis,
                                                const float* __restrict__ b2,
                                                const float* __restrict__ l1b,
                                                const float* __restrict__ l2b,
                                                const float* __restrict__ W30,
                                                const float* __restrict__ W31,
                                                const float* __restrict__ b3,
                                                float* __restrict__ out,
                                                float* __restrict__ qbuf,
                                                unsigned char* __restrict__ zf8) {
    int tid = threadIdx.x;
    int wave = tid >> 6, lane = tid & 63, ml = lane & 15, quad = lane >> 4;
    int row0 = blockIdx.x * 64;
    int rw = row0 + wave * 16;
    if (rw >= NN) return;

    int ar = rw + ml; if (ar >= NN) ar = NN - 1;
    const bf16x8* Ap = (const bf16x8*)(xcat + (size_t)ar * 128 + quad * 8);
    bf16x8 a0 = Ap[0], a1 = Ap[4];
    float p0[4] = {0, 0, 0, 0}, p1[4] = {0, 0, 0, 0};
    float b3v = b3[0];

    for (int nt = 0; nt < 13; nt++) {
        bf16x8 bw0 = *(const bf16x8*)(Wtlf + (size_t)((nt * 2 + 0) * 64 + lane) * 8);
        bf16x8 bw1 = *(const bf16x8*)(Wtlf + (size_t)((nt * 2 + 1) * 64 + lane) * 8);
        f32x4 acc = {0.f, 0.f, 0.f, 0.f};
        acc = __builtin_amdgcn_mfma_f32_16x16x32_bf16(a0, bw0, acc, 0, 0, 0);
        acc = __builtin_amdgcn_mfma_f32_16x16x32_bf16(a1, bw1, acc, 0, 0, 0);
        int j = nt * 16 + ml;
        int jj = (j < 104) ? j : j - 104;
        float bb = 0.0f, lb = 0.0f;
        if (jj < 100) {
            bb = b2[jj];
            lb = (j < 104) ? l1b[jj] : l2b[jj];
        }
        float w0 = (j < 100) ? W30[j] : 0.0f;
        float w1 = (j < 100) ? W31[j] : 0.0f;
#pragma unroll
        for (int r = 0; r < 4; r++) {
            int row = rw + quad * 4 + r;
            int rcl = row < NN ? row : NN - 1;
            float x1v = hp[(size_t)rcl * 104 + jj] + tx2[(size_t)rcl * 104 + jj] + bb;
            x1v = x1v > 0.0f ? x1v : 0.0f;
            float lv = acc[r] + lb;
            lv = lv > 0.0f ? lv : 0.0f;
            float o = x1v + lv;
            if (j < 104) {
                p0[r] += o * w0;
                p1[r] += o * w1;
            } else if (row < NN) {
                zf8[(size_t)row * 128 + (j - 104)] = f2e4m3(o);
            }
        }
    }
#pragma unroll
    for (int m = 1; m < 16; m <<= 1) {
#pragma unroll
        for (int r = 0; r < 4; r++) {
            p0[r] += __shfl_xor(p0[r], m, 64);
            p1[r] += __shfl_xor(p1[r], m, 64);
        }
    }
    if (ml == 0) {
#pragma unroll
        for (int r = 0; r < 4; r++) {
            int row = rw + quad * 4 + r;
            if (row < NN) {
                out[row] = p0[r] + b3v;
                qbuf[row] = dis[row] * p1[r];
            }
        }
    }
    // zero zf8 pad cols 104..127 for this wave's 16 rows
    for (int idx = lane; idx < 16 * 6; idx += 64) {
        int rr = rw + idx / 6;
        if (rr < NN) *(unsigned*)(zf8 + (size_t)rr * 128 + 104 + (idx % 6) * 4) = 0u;
    }
}

// ------- pure edge scores via fp8 MFMA -> pbuf ----------
__global__ __launch_bounds__(256) void k_score(const unsigned char* __restrict__ zf8,
                                               const int* __restrict__ ei,
                                               const int* __restrict__ nei,
                                               float* __restrict__ pbuf) {
    int lane = threadIdx.x & 63;
    int wid = (blockIdx.x * 256 + threadIdx.x) >> 6;
    int nw = SB2 * 4;
    int ml = lane & 15, quad = lane >> 4;
    int dr = ml - quad * 4;
    bool diag = (dr >= 0 && dr < 4);
    const int G = (2 * NE) / 16;
    for (int g = wid; g < G; g += nw) {
        int base = g * 16;
        int a, b;
        if (base < NE) {
            a = ei[base + ml];
            b = ei[NE + base + ml];
        } else {
            a = nei[base - NE + ml];
            b = nei[base + ml];
        }
        i32x8 av = *(const i32x8*)(zf8 + (size_t)a * 128 + quad * 32);
        i32x8 bv = *(const i32x8*)(zf8 + (size_t)b * 128 + quad * 32);
        f32x4 d = {0.f, 0.f, 0.f, 0.f};
        d = __builtin_amdgcn_mfma_scale_f32_16x16x128_f8f6f4(
                av, bv, d, 0, 0, 0, 0x7f7f7f7f, 0, 0x7f7f7f7f);
        if (diag) pbuf[base + ml] = d[dr];
    }
}

// ------- dense transcendentals + block partial sums ----------
__global__ __launch_bounds__(256) void k_loss(const float* __restrict__ pbuf,
                                              double* __restrict__ red) {
    double acc = 0.0;
    for (int i = blockIdx.x * 256 + threadIdx.x; i < 2 * NE; i += LB * 256) {
        float p = pbuf[i];
        float sg = 1.0f / (1.0f + expf(-p));
        float term = (i < NE) ? logf(sg + 1e-15f) : logf(1.0f - sg + 1e-15f);
        acc += (double)term;
    }
    __shared__ double sred[256];
    sred[threadIdx.x] = acc;
    __syncthreads();
    for (int s = 128; s; s >>= 1) {
        if (threadIdx.x < s) sred[threadIdx.x] += sred[threadIdx.x + s];
        __syncthreads();
    }
    if (threadIdx.x == 0) red[blockIdx.x] = sred[0];
}

// ------- fused: final loss reduction (block 0) + layer3 gather (rest) --------
__global__ __launch_bounds__(256) void k_final_g1(const double* __restrict__ red,
                                                  const float* __restrict__ c1,
                                                  const float* __restrict__ c2,
                                                  const int* __restrict__ cnt,
                                                  const unsigned short* __restrict__ bkt16,
                                                  const float* __restrict__ dis,
                                                  const float* __restrict__ qbuf,
                                                  float* __restrict__ out) {
    if (blockIdx.x == 0) {
        double a = 0.0;
        for (int i = threadIdx.x; i < LB; i += 256) a += red[i];
        __shared__ double sred[256];
        sred[threadIdx.x] = a;
        __syncthreads();
        for (int st = 128; st; st >>= 1) {
            if (threadIdx.x < st) sred[threadIdx.x] += sred[threadIdx.x + st];
            __syncthreads();
        }
        if (threadIdx.x == 0) {
            out[NN] = (float)(-sred[0] / (double)NE);
            out[NN + 1] = c1[0];
            out[NN + 2] = c2[0];
        }
        return;
    }
    int n = (blockIdx.x - 1) * 256 + threadIdx.x;
    if (n >= NN) return;
    int c = cnt[n]; if (c > CAP) c = CAP;
    const unsigned short* bp = bkt16 + (n << 6);
    float acc = 0.0f;
    for (int i = 0; i < c; i++) acc += qbuf[bp[i]];
    out[n] += -dis[n] * acc;
}

extern "C" void kernel_launch(void* const* d_in, const int* in_sizes, int n_in,
                              void* d_out, int out_size, void* d_ws, size_t ws_size,
                              hipStream_t stream) {
    const float* x    = (const float*)d_in[0];
    const int*   ei   = (const int*)d_in[1];
    const int*   nei  = (const int*)d_in[2];
    const float* W1_0 = (const float*)d_in[3];
    const float* W1_1 = (const float*)d_in[4];
    const float* b1   = (const float*)d_in[5];
    const float* W2_0 = (const float*)d_in[6];
    const float* W2_1 = (const float*)d_in[7];
    const float* b2   = (const float*)d_in[8];
    const float* W3_0 = (const float*)d_in[9];
    const float* W3_1 = (const float*)d_in[10];
    const float* b3   = (const float*)d_in[11];
    const float* l1W  = (const float*)d_in[12];
    const float* l1b  = (const float*)d_in[13];
    const float* l2W  = (const float*)d_in[14];
    const float* l2b  = (const float*)d_in[15];
    const float* c1   = (const float*)d_in[16];
    const float* c2   = (const float*)d_in[17];
    float* out = (float*)d_out;
    float* w = (float*)d_ws;

    // workspace (float offsets)
    unsigned short* bkt16  = (unsigned short*)w;                  // NN*64 u16
    int*            degs   = (int*)(w + 1600000);                 // 50000 [zeroed]
    int*            cnt    = (int*)(w + 1650000);                 // 50000 [zeroed]
    float*          dis    = w + 1700000;                         // 50000
    float*          qbuf   = w + 1750000;                         // 50000
    double*         red    = (double*)(w + 1800000);              // 1024 doubles
    float*          pbuf   = w + 1802048;                         // 1.6M floats
    unsigned short* xcat   = (unsigned short*)(w + 3402048);      // N*128 bf16
    unsigned short* Wt1f   = (unsigned short*)(w + 6602048);      // 40960 bf16
    unsigned short* Wt2f   = (unsigned short*)(w + 6622528);      // 66560 bf16
    unsigned short* Wtlf   = (unsigned short*)(w + 6655808);      // 13312 bf16
    float*          hp     = w + 6662464;                         // N*104 f
    unsigned char*  hwf8   = (unsigned char*)(w + 11862464);      // N*128 bytes
    unsigned char*  zf8    = (unsigned char*)(w + 13462464);      // N*128 bytes
    unsigned char*  xf8    = (unsigned char*)(w + 15062464);      // N*64 bytes
    float*          tx2    = w + 15862464;                        // N*104 f

    hipMemsetAsync(degs, 0, 100000 * sizeof(int), stream);  // degs + cnt contiguous

    k_build<<<(NE + 255) / 256, 256, 0, stream>>>(ei, degs, cnt, bkt16);
    k_prep<<<13168, 256, 0, stream>>>(x, xcat, xf8, degs, dis,
                                      W1_0, W1_1, W2_0, W2_1, l1W, l2W,
                                      Wt1f, Wt2f, Wtlf);

    k_gather58<<<(NN * 8 + 255) / 256, 256, 0, stream>>>(cnt, bkt16, dis, xf8, xcat);
    k_mm12<<<(NN + 63) / 64, 256, 0, stream>>>(xcat, Wt1f, b1, Wt2f, dis, hp, hwf8);

    k_gather100<<<NN * 16 / 256, 256, 0, stream>>>(cnt, bkt16, dis, hwf8, tx2);
    k_mmlin3<<<(NN + 63) / 64, 256, 0, stream>>>(xcat, Wtlf, hp, tx2, dis,
                                                 b2, l1b, l2b, W3_0, W3_1, b3,
                                                 out, qbuf, zf8);

    k_score<<<SB2, 256, 0, stream>>>(zf8, ei, nei, pbuf);
    k_loss<<<LB, 256, 0, stream>>>(pbuf, red);
    k_final_g1<<<1 + (NN + 255) / 256, 256, 0, stream>>>(red, c1, c2, cnt, bkt16, dis, qbuf, out);
}